// Round 2
// baseline (5814.508 us; speedup 1.0000x reference)
//
#include <hip/hip_runtime.h>
#include <hip/hip_bf16.h>

// Problem constants
#define SEQ    70
#define BATCH  128
#define HID    512
#define EMB    512
#define VOCAB  10000
#define VPAD   10112            // VOCAB padded to multiple of 128
#define MROWS  (SEQ*BATCH)      // 8960
#define LOGITS_ELEMS (89600000) // SEQ*BATCH*VOCAB
#define NWG    256              // persistent-loop workgroups (1 per CU)

typedef float  floatx4 __attribute__((ext_vector_type(4)));
typedef short  shortx8 __attribute__((ext_vector_type(8)));

__device__ __forceinline__ unsigned short f2b(float f) {
    unsigned int u = __builtin_bit_cast(unsigned int, f);
    unsigned int r = (u + 0x7fff + ((u >> 16) & 1)) >> 16;   // RNE
    return (unsigned short)r;
}
__device__ __forceinline__ void split_bf16(float x, unsigned short& hi, unsigned short& lo) {
    hi = f2b(x);
    float fh = __builtin_bit_cast(float, (unsigned int)hi << 16);
    lo = f2b(x - fh);
}
__device__ __forceinline__ float sigmoidf_(float x) { return 1.f / (1.f + __expf(-x)); }

// ---------------------------------------------------------------------------
// transpose + fp32->bf16 convert:  src (512 x C) -> dst (Npad x 512), pad rows = 0
__global__ void transpose_conv(const float* __restrict__ src, unsigned short* __restrict__ dst,
                               int C, int Npad) {
    __shared__ float tile[32][33];
    int r0 = blockIdx.x * 32, c0 = blockIdx.y * 32;
    int tx = threadIdx.x, ty = threadIdx.y;       // tx 0..31, ty 0..7
    #pragma unroll
    for (int i = 0; i < 32; i += 8) {
        int r = r0 + ty + i, c = c0 + tx;
        tile[ty + i][tx] = (c < C) ? src[(size_t)r * C + c] : 0.f;
    }
    __syncthreads();
    #pragma unroll
    for (int i = 0; i < 32; i += 8) {
        int dr = c0 + ty + i;      // dest row = source col
        int dc = r0 + tx;          // dest col = source row
        dst[(size_t)dr * 512 + dc] = f2b(tile[tx][ty + i]);
    }
}

// transpose + hi/lo split:  src (512 x C) f32 -> dsth/dstl (C x 512) bf16. C multiple of 32.
__global__ void transpose_split(const float* __restrict__ src, unsigned short* __restrict__ dh,
                                unsigned short* __restrict__ dl, int C) {
    __shared__ float tile[32][33];
    int r0 = blockIdx.x * 32, c0 = blockIdx.y * 32;
    int tx = threadIdx.x, ty = threadIdx.y;
    #pragma unroll
    for (int i = 0; i < 32; i += 8)
        tile[ty + i][tx] = src[(size_t)(r0 + ty + i) * C + c0 + tx];
    __syncthreads();
    #pragma unroll
    for (int i = 0; i < 32; i += 8) {
        int dr = c0 + ty + i, dc = r0 + tx;
        unsigned short hi, lo;
        split_bf16(tile[tx][ty + i], hi, lo);
        dh[(size_t)dr * 512 + dc] = hi;
        dl[(size_t)dr * 512 + dc] = lo;
    }
}

// embedding gather + convert
__global__ void gather_conv(const int* __restrict__ idx, const float* __restrict__ emb,
                            unsigned short* __restrict__ E) {
    int row = blockIdx.x;
    int t = threadIdx.x;
    int id = idx[row];
    const float4 v = *(const float4*)&emb[(size_t)id * EMB + t * 4];
    ushort4 o;
    o.x = f2b(v.x); o.y = f2b(v.y); o.z = f2b(v.z); o.w = f2b(v.w);
    *(ushort4*)&E[(size_t)row * EMB + t * 4] = o;
}

__global__ void hinit_split(const float* __restrict__ hid,
                            float* __restrict__ h0f, unsigned short* __restrict__ h0h, unsigned short* __restrict__ h0l,
                            float* __restrict__ h1f, unsigned short* __restrict__ h1h, unsigned short* __restrict__ h1l) {
    int i = blockIdx.x * 256 + threadIdx.x;   // 65536 threads
    float a = hid[i], b = hid[65536 + i];
    unsigned short hi, lo;
    h0f[i] = a; split_bf16(a, hi, lo); h0h[i] = hi; h0l[i] = lo;
    h1f[i] = b; split_bf16(b, hi, lo); h1h[i] = hi; h1l[i] = lo;
}

__global__ void tail_copy(const float* __restrict__ h0, const float* __restrict__ h1,
                          float* __restrict__ out) {
    int i = blockIdx.x * 256 + threadIdx.x;   // 131072 threads
    out[LOGITS_ELEMS + i] = (i < 65536) ? h0[i] : h1[i - 65536];
}

// ---------------------------------------------------------------------------
// bf16 MFMA GEMM (m97 recipe): C[M x Nlog] = A[M x 512] * Bt[Npad x 512]^T + bias
__global__ __launch_bounds__(256) void gemm_bt(const unsigned short* __restrict__ A,
                                               const unsigned short* __restrict__ Bt,
                                               const float* __restrict__ bias,
                                               float* __restrict__ C,
                                               int Nlog, int ldc) {
    constexpr int K = 512;
    __shared__ __align__(16) unsigned short As[128 * 32];
    __shared__ __align__(16) unsigned short Bs[128 * 32];
    int m0 = blockIdx.x * 128, n0 = blockIdx.y * 128;
    int tid = threadIdx.x, lane = tid & 63, w = tid >> 6;
    int wm = w >> 1, wn = w & 1;
    int quad = lane >> 4, l16 = lane & 15;
    floatx4 acc[4][4] = {};

    for (int kc = 0; kc < K; kc += 32) {
        #pragma unroll
        for (int j = 0; j < 2; ++j) {
            int chunk = j * 256 + tid;
            int row = chunk >> 2, cc = chunk & 3;
            const unsigned short* g = A + (size_t)(m0 + row) * K + kc + cc * 8;
            unsigned short* l = As + (size_t)(j * 256 + w * 64) * 8;
            __builtin_amdgcn_global_load_lds((__attribute__((address_space(1))) const unsigned int*)g,
                                             (__attribute__((address_space(3))) unsigned int*)l, 16, 0, 0);
        }
        #pragma unroll
        for (int j = 0; j < 2; ++j) {
            int chunk = j * 256 + tid;
            int row = chunk >> 2, cc = chunk & 3;
            const unsigned short* g = Bt + (size_t)(n0 + row) * K + kc + cc * 8;
            unsigned short* l = Bs + (size_t)(j * 256 + w * 64) * 8;
            __builtin_amdgcn_global_load_lds((__attribute__((address_space(1))) const unsigned int*)g,
                                             (__attribute__((address_space(3))) unsigned int*)l, 16, 0, 0);
        }
        __syncthreads();
        shortx8 af[4], bfv[4];
        #pragma unroll
        for (int i = 0; i < 4; ++i)
            af[i] = *(const shortx8*)&As[(wm * 64 + i * 16 + l16) * 32 + quad * 8];
        #pragma unroll
        for (int i = 0; i < 4; ++i)
            bfv[i] = *(const shortx8*)&Bs[(wn * 64 + i * 16 + l16) * 32 + quad * 8];
        #pragma unroll
        for (int i = 0; i < 4; ++i)
            #pragma unroll
            for (int jn = 0; jn < 4; ++jn)
                acc[i][jn] = __builtin_amdgcn_mfma_f32_16x16x32_bf16(af[i], bfv[jn], acc[i][jn], 0, 0, 0);
        __syncthreads();
    }
    #pragma unroll
    for (int i = 0; i < 4; ++i) {
        int row = m0 + wm * 64 + i * 16 + quad * 4;
        #pragma unroll
        for (int jn = 0; jn < 4; ++jn) {
            int col = n0 + wn * 64 + jn * 16 + l16;
            if (col < Nlog) {
                float bb = bias ? bias[col] : 0.f;
                #pragma unroll
                for (int r = 0; r < 4; ++r)
                    C[(size_t)(row + r) * ldc + col] = acc[i][jn][r] + bb;
            }
        }
    }
}

// ---------------------------------------------------------------------------
// Recurrent GEMM core: per block (256 thr, 4 waves) computes C[64 x 16] over K=512
// with bf16 hi/lo split (3 MFMA products). A pointers pre-offset to the 64-row base;
// B pointers pre-offset to the 16-col tile (N x K layout).
__device__ __forceinline__ floatx4 rgemm64(const unsigned short* __restrict__ Ah,
                                           const unsigned short* __restrict__ Al,
                                           const unsigned short* __restrict__ Bh,
                                           const unsigned short* __restrict__ Bl,
                                           int tid) {
    int lane = tid & 63, w = tid >> 6, l16 = lane & 15, quad = lane >> 4;
    const unsigned short* ah = Ah + (size_t)(w * 16 + l16) * 512 + quad * 8;
    const unsigned short* al = Al + (size_t)(w * 16 + l16) * 512 + quad * 8;
    const unsigned short* bh = Bh + (size_t)l16 * 512 + quad * 8;
    const unsigned short* bl = Bl + (size_t)l16 * 512 + quad * 8;
    floatx4 acc = {};
    #pragma unroll
    for (int ks = 0; ks < 16; ++ks) {
        shortx8 vbh = *(const shortx8*)(bh + ks * 32);
        shortx8 vbl = *(const shortx8*)(bl + ks * 32);
        shortx8 vah = *(const shortx8*)(ah + ks * 32);
        shortx8 val = *(const shortx8*)(al + ks * 32);
        acc = __builtin_amdgcn_mfma_f32_16x16x32_bf16(vah, vbh, acc, 0, 0, 0);
        acc = __builtin_amdgcn_mfma_f32_16x16x32_bf16(val, vbh, acc, 0, 0, 0);
        acc = __builtin_amdgcn_mfma_f32_16x16x32_bf16(vah, vbl, acc, 0, 0, 0);
    }
    return acc;
}

// ---------------------------------------------------------------------------
// Device-scope grid barrier (single-counter, generation-based).
// Co-residency of all NWG workgroups is GUARANTEED by cooperative launch
// (hipLaunchCooperativeKernel refuses to launch otherwise — no silent hang).
// Release fence -> L2 writeback (cross-XCD visibility of our stores); acquire
// fence -> L1/L2 invalidate (so we see other XCDs' stores).
// Replay-safe: protocol is correct for any initial 'gen' provided cnt==0, and
// every complete pass ends with cnt==0.
__device__ __forceinline__ void grid_sync(unsigned* bar) {
    __syncthreads();                 // compiler emits s_waitcnt vmcnt(0) before s_barrier
    if (threadIdx.x == 0) {
        unsigned* cnt = bar;
        unsigned* gen = bar + 32;    // separate cacheline
        unsigned g0 = __hip_atomic_load(gen, __ATOMIC_RELAXED, __HIP_MEMORY_SCOPE_AGENT);
        __builtin_amdgcn_fence(__ATOMIC_RELEASE, "agent");
        unsigned prev = __hip_atomic_fetch_add(cnt, 1u, __ATOMIC_RELAXED, __HIP_MEMORY_SCOPE_AGENT);
        if (prev == NWG - 1u) {
            __hip_atomic_store(cnt, 0u, __ATOMIC_RELAXED, __HIP_MEMORY_SCOPE_AGENT);
            // RELEASE: orders the cnt reset before the generation bump
            __hip_atomic_store(gen, g0 + 1u, __ATOMIC_RELEASE, __HIP_MEMORY_SCOPE_AGENT);
        } else {
            while (__hip_atomic_load(gen, __ATOMIC_RELAXED, __HIP_MEMORY_SCOPE_AGENT) == g0)
                __builtin_amdgcn_s_sleep(2);
        }
        __builtin_amdgcn_fence(__ATOMIC_ACQUIRE, "agent");
    }
    __syncthreads();
}

__global__ void bar_init(unsigned* bar) { bar[0] = 0u; bar[32] = 0u; }

// ---------------------------------------------------------------------------
// Persistent recurrent loop: one kernel, 70 timesteps, 4 phases/step separated
// by grid_sync. Phase->WG mapping identical to the old per-phase grids.
struct GruArgs {
    const unsigned short *Uh0h, *Uh0l, *Uh1h, *Uh1l;
    const unsigned short *Ut0h, *Ut0l;
    const unsigned short *Wx1h, *Wx1l;
    const unsigned short *Ut1h, *Ut1l;
    const float *G0, *b1;
    float *h0f[2], *h1f[2];
    unsigned short *h0h[2], *h0l[2], *h1h[2], *h1l[2];
    unsigned short *rh0h, *rh0l, *rh1h, *rh1l;
    float *z0, *z1, *u1, *wh1;
    unsigned short *H1b;
    unsigned *bar;
};

__global__ __launch_bounds__(256, 1) void gru_loop(GruArgs g) {
    const int wg = blockIdx.x;            // 0..255
    const int tid = threadIdx.x;
    const int lane = tid & 63, w = tid >> 6, l16 = lane & 15, quad = lane >> 4;

    #pragma unroll 1
    for (int t = 0; t < 70; ++t) {
        const int rd = t & 1;             // read index (t even: 'a' set)
        const int wr = rd ^ 1;

        // ---- phase 1: u0 = h0@U_h0 (tiles 0..63) | u1 = h1@U_h1 (64..127) ----
        {
            int tile = wg >> 1, mh = wg & 1, rb = mh * 64;
            const unsigned short *Ah, *Al, *Bh, *Bl;
            if (tile < 64) {
                Ah = g.h0h[rd]; Al = g.h0l[rd];
                Bh = g.Uh0h + (size_t)tile * 16 * 512;
                Bl = g.Uh0l + (size_t)tile * 16 * 512;
            } else {
                Ah = g.h1h[rd]; Al = g.h1l[rd];
                Bh = g.Uh1h + (size_t)(tile - 64) * 16 * 512;
                Bl = g.Uh1l + (size_t)(tile - 64) * 16 * 512;
            }
            floatx4 acc = rgemm64(Ah + (size_t)rb * 512, Al + (size_t)rb * 512, Bh, Bl, tid);
            int rowb = rb + w * 16 + quad * 4;
            if (tile < 32) {
                int col = tile * 16 + l16;
                #pragma unroll
                for (int r = 0; r < 4; ++r) {
                    int row = rowb + r;
                    float rg = sigmoidf_(g.G0[(size_t)(t * 128 + row) * 1536 + col] + acc[r]);
                    float rh = rg * g.h0f[rd][row * 512 + col];
                    unsigned short hi, lo; split_bf16(rh, hi, lo);
                    g.rh0h[row * 512 + col] = hi; g.rh0l[row * 512 + col] = lo;
                }
            } else if (tile < 64) {
                int col = (tile - 32) * 16 + l16;
                #pragma unroll
                for (int r = 0; r < 4; ++r) {
                    int row = rowb + r;
                    g.z0[row * 512 + col] = sigmoidf_(g.G0[(size_t)(t * 128 + row) * 1536 + 512 + col] + acc[r]);
                }
            } else {
                int col = (tile - 64) * 16 + l16;
                #pragma unroll
                for (int r = 0; r < 4; ++r) {
                    int row = rowb + r;
                    g.u1[row * 1024 + col] = acc[r];
                }
            }
        }
        grid_sync(g.bar);

        // ---- phase 2: v0 = rh0@U_ht0; h0' = (1-z0)h0 + z0 tanh(G0wh + v0) ----
        if (wg < 64) {
            int tile = wg >> 1, mh = wg & 1, rb = mh * 64;
            floatx4 acc = rgemm64(g.rh0h + (size_t)rb * 512, g.rh0l + (size_t)rb * 512,
                                  g.Ut0h + (size_t)tile * 16 * 512, g.Ut0l + (size_t)tile * 16 * 512, tid);
            int rowb = rb + w * 16 + quad * 4;
            int col = tile * 16 + l16;
            #pragma unroll
            for (int r = 0; r < 4; ++r) {
                int row = rowb + r;
                float ht = tanhf(g.G0[(size_t)(t * 128 + row) * 1536 + 1024 + col] + acc[r]);
                float z  = g.z0[row * 512 + col];
                float hn = (1.f - z) * g.h0f[rd][row * 512 + col] + z * ht;
                g.h0f[wr][row * 512 + col] = hn;
                unsigned short hi, lo; split_bf16(hn, hi, lo);
                g.h0h[wr][row * 512 + col] = hi; g.h0l[wr][row * 512 + col] = lo;
            }
        }
        grid_sync(g.bar);

        // ---- phase 3: g1 = h0'@W_x1 + b1; epilogue by col region ----
        if (wg < 192) {
            int tile = wg >> 1, mh = wg & 1, rb = mh * 64;
            floatx4 acc = rgemm64(g.h0h[wr] + (size_t)rb * 512, g.h0l[wr] + (size_t)rb * 512,
                                  g.Wx1h + (size_t)tile * 16 * 512, g.Wx1l + (size_t)tile * 16 * 512, tid);
            int rowb = rb + w * 16 + quad * 4;
            int col = tile * 16 + l16;          // 0..1535
            float bb = g.b1[col];
            if (col < 512) {
                #pragma unroll
                for (int r = 0; r < 4; ++r) {
                    int row = rowb + r;
                    float r1 = sigmoidf_(acc[r] + bb + g.u1[row * 1024 + col]);
                    float rh = r1 * g.h1f[rd][row * 512 + col];
                    unsigned short hi, lo; split_bf16(rh, hi, lo);
                    g.rh1h[row * 512 + col] = hi; g.rh1l[row * 512 + col] = lo;
                }
            } else if (col < 1024) {
                int c = col - 512;
                #pragma unroll
                for (int r = 0; r < 4; ++r) {
                    int row = rowb + r;
                    g.z1[row * 512 + c] = sigmoidf_(acc[r] + bb + g.u1[row * 1024 + col]);
                }
            } else {
                int c = col - 1024;
                #pragma unroll
                for (int r = 0; r < 4; ++r) {
                    int row = rowb + r;
                    g.wh1[row * 512 + c] = acc[r] + bb;
                }
            }
        }
        grid_sync(g.bar);

        // ---- phase 4: v1 = rh1@U_ht1; h1' = (1-z1)h1 + z1 tanh(wh1 + v1) ----
        if (wg < 64) {
            int tile = wg >> 1, mh = wg & 1, rb = mh * 64;
            floatx4 acc = rgemm64(g.rh1h + (size_t)rb * 512, g.rh1l + (size_t)rb * 512,
                                  g.Ut1h + (size_t)tile * 16 * 512, g.Ut1l + (size_t)tile * 16 * 512, tid);
            int rowb = rb + w * 16 + quad * 4;
            int col = tile * 16 + l16;
            #pragma unroll
            for (int r = 0; r < 4; ++r) {
                int row = rowb + r;
                float ht = tanhf(g.wh1[row * 512 + col] + acc[r]);
                float z  = g.z1[row * 512 + col];
                float hn = (1.f - z) * g.h1f[rd][row * 512 + col] + z * ht;
                g.h1f[wr][row * 512 + col] = hn;
                unsigned short hi, lo; split_bf16(hn, hi, lo);
                g.h1h[wr][row * 512 + col] = hi; g.h1l[wr][row * 512 + col] = lo;
                g.H1b[(size_t)(t * 128 + row) * 512 + col] = hi;
            }
        }
        grid_sync(g.bar);
    }
}

// ---------------------------------------------------------------------------
extern "C" void kernel_launch(void* const* d_in, const int* in_sizes, int n_in,
                              void* d_out, int out_size, void* d_ws, size_t ws_size,
                              hipStream_t stream) {
    const int*   inputs = (const int*)  d_in[0];
    const float* hidden = (const float*)d_in[1];
    const float* emb    = (const float*)d_in[2];
    const float* Wx0    = (const float*)d_in[3];
    const float* Uh0    = (const float*)d_in[4];
    const float* Uht0   = (const float*)d_in[5];
    const float* b0     = (const float*)d_in[6];
    const float* Wx1    = (const float*)d_in[7];
    const float* Uh1    = (const float*)d_in[8];
    const float* Uht1   = (const float*)d_in[9];
    const float* b1     = (const float*)d_in[10];
    const float* decW   = (const float*)d_in[11];
    const float* decb   = (const float*)d_in[12];
    float* out = (float*)d_out;

    char* ws = (char*)d_ws;
    size_t off = 0;
    auto take = [&](size_t bytes) -> char* {
        char* p = ws + off;
        off += (bytes + 255) & ~(size_t)255;
        return p;
    };
    float*          G0   = (float*)         take((size_t)MROWS * 1536 * 4);
    unsigned short* Eb   = (unsigned short*)take((size_t)MROWS * 512 * 2);
    unsigned short* Wx0t = (unsigned short*)take((size_t)1536 * 512 * 2);
    unsigned short* dWt  = (unsigned short*)take((size_t)VPAD * 512 * 2);
    unsigned short* H1b  = (unsigned short*)take((size_t)MROWS * 512 * 2);
    // transposed hi/lo weights (N x 512 bf16)
    unsigned short* Uh0h = (unsigned short*)take(1024 * 512 * 2);
    unsigned short* Uh0l = (unsigned short*)take(1024 * 512 * 2);
    unsigned short* Ut0h = (unsigned short*)take(512 * 512 * 2);
    unsigned short* Ut0l = (unsigned short*)take(512 * 512 * 2);
    unsigned short* Wx1h = (unsigned short*)take(1536 * 512 * 2);
    unsigned short* Wx1l = (unsigned short*)take(1536 * 512 * 2);
    unsigned short* Uh1h = (unsigned short*)take(1024 * 512 * 2);
    unsigned short* Uh1l = (unsigned short*)take(1024 * 512 * 2);
    unsigned short* Ut1h = (unsigned short*)take(512 * 512 * 2);
    unsigned short* Ut1l = (unsigned short*)take(512 * 512 * 2);
    // state (ping-pong)
    float* h0f_a = (float*)take(65536 * 4);  float* h0f_b = (float*)take(65536 * 4);
    float* h1f_a = (float*)take(65536 * 4);  float* h1f_b = (float*)take(65536 * 4);
    unsigned short* h0h_a = (unsigned short*)take(65536 * 2);
    unsigned short* h0h_b = (unsigned short*)take(65536 * 2);
    unsigned short* h0l_a = (unsigned short*)take(65536 * 2);
    unsigned short* h0l_b = (unsigned short*)take(65536 * 2);
    unsigned short* h1h_a = (unsigned short*)take(65536 * 2);
    unsigned short* h1h_b = (unsigned short*)take(65536 * 2);
    unsigned short* h1l_a = (unsigned short*)take(65536 * 2);
    unsigned short* h1l_b = (unsigned short*)take(65536 * 2);
    // per-step scratch
    unsigned short* rh0h = (unsigned short*)take(65536 * 2);
    unsigned short* rh0l = (unsigned short*)take(65536 * 2);
    unsigned short* rh1h = (unsigned short*)take(65536 * 2);
    unsigned short* rh1l = (unsigned short*)take(65536 * 2);
    float* z0  = (float*)take(65536 * 4);
    float* z1  = (float*)take(65536 * 4);
    float* u1  = (float*)take(131072 * 4);
    float* wh1 = (float*)take(65536 * 4);
    unsigned* bar = (unsigned*)take(256);

    // setup
    bar_init<<<1, 1, 0, stream>>>(bar);
    transpose_conv<<<dim3(16, 48),  dim3(32, 8), 0, stream>>>(Wx0,  Wx0t, 1536, 1536);
    transpose_conv<<<dim3(16, 316), dim3(32, 8), 0, stream>>>(decW, dWt, VOCAB, VPAD);
    transpose_split<<<dim3(16, 32), dim3(32, 8), 0, stream>>>(Uh0,  Uh0h, Uh0l, 1024);
    transpose_split<<<dim3(16, 16), dim3(32, 8), 0, stream>>>(Uht0, Ut0h, Ut0l, 512);
    transpose_split<<<dim3(16, 48), dim3(32, 8), 0, stream>>>(Wx1,  Wx1h, Wx1l, 1536);
    transpose_split<<<dim3(16, 32), dim3(32, 8), 0, stream>>>(Uh1,  Uh1h, Uh1l, 1024);
    transpose_split<<<dim3(16, 16), dim3(32, 8), 0, stream>>>(Uht1, Ut1h, Ut1l, 512);
    gather_conv<<<MROWS, 128, 0, stream>>>(inputs, emb, Eb);
    hinit_split<<<256, 256, 0, stream>>>(hidden, h0f_a, h0h_a, h0l_a, h1f_a, h1h_a, h1l_a);

    // G0 = E @ W_x0 + b0  (all timesteps at once)
    gemm_bt<<<dim3(70, 12), 256, 0, stream>>>(Eb, Wx0t, b0, G0, 1536, 1536);

    // persistent recurrent loop (replaces 280 per-step dispatches).
    // Cooperative launch => co-residency guaranteed (fails loudly instead of
    // deadlocking if the grid could not be fully resident).
    GruArgs ga;
    ga.Uh0h = Uh0h; ga.Uh0l = Uh0l; ga.Uh1h = Uh1h; ga.Uh1l = Uh1l;
    ga.Ut0h = Ut0h; ga.Ut0l = Ut0l;
    ga.Wx1h = Wx1h; ga.Wx1l = Wx1l;
    ga.Ut1h = Ut1h; ga.Ut1l = Ut1l;
    ga.G0 = G0; ga.b1 = b1;
    ga.h0f[0] = h0f_a; ga.h0f[1] = h0f_b;
    ga.h1f[0] = h1f_a; ga.h1f[1] = h1f_b;
    ga.h0h[0] = h0h_a; ga.h0h[1] = h0h_b;
    ga.h0l[0] = h0l_a; ga.h0l[1] = h0l_b;
    ga.h1h[0] = h1h_a; ga.h1h[1] = h1h_b;
    ga.h1l[0] = h1l_a; ga.h1l[1] = h1l_b;
    ga.rh0h = rh0h; ga.rh0l = rh0l; ga.rh1h = rh1h; ga.rh1l = rh1l;
    ga.z0 = z0; ga.z1 = z1; ga.u1 = u1; ga.wh1 = wh1;
    ga.H1b = H1b; ga.bar = bar;
    void* kargs[] = { (void*)&ga };
    hipLaunchCooperativeKernel((const void*)gru_loop, dim3(NWG), dim3(256),
                               kargs, 0, stream);

    // logits = H1 @ dec_W + dec_b   -> d_out
    gemm_bt<<<dim3(70, 79), 256, 0, stream>>>(H1b, dWt, decb, out, VOCAB, VOCAB);

    // final hidden (70 even -> final state in the 'a' set)
    tail_copy<<<512, 256, 0, stream>>>(h0f_a, h1f_a, out);
}